// Round 1
// 178.910 us; speedup vs baseline: 1.0462x; 1.0462x over previous
//
#include <hip/hip_runtime.h>
#include <hip/hip_bf16.h>

// PAM module R7: q/k/v 1x1 projections -> bf16 MFMA attention -> gamma*out + x.
// R6 post-mortem: attn is latency-bound, not pipe-bound (MfmaUtil 30% ==
// VALUBusy 30%, HBM 5.7%). The per-tile chain S->exp->bpermute->PV is fully
// serial within a wave and only 2 waves/SIMD are resident (unified-reg limited)
// so the MFMA and VALU pipes never overlap. R7: dual-sacc software pipeline --
// softmax(t) is hand-interleaved with the S-MFMAs of tile t+1 (independent,
// K(t+1) already in the register ping-pong), then PV(t). Also: log2e folded
// into the Q projection weights so softmax is a bare v_exp_f32, and sacc
// zero-init folded into the kc=0 MFMA (C = zero vector).
//
// Workspace layouts (bf16, chunk = 64 lanes x 16B = 1KB, frag-major):
//   qf_ws[b][strip32][ni2][kc4][lane]         8MB  (PRE-SCALED by log2e)
//   kt   [b][tile128][mb8][kc4][lane]         8MB
//   vt   [b][tile128][cb*16+wq][l16]{8}       8MB

typedef __bf16 v8bf __attribute__((ext_vector_type(8)));
typedef float  v4f  __attribute__((ext_vector_type(4)));

#define B_ 8
#define C_ 128
#define N_ 4096

static __device__ __forceinline__ unsigned short f2bf_rne(float f) {
    union { float f; unsigned u; } v; v.f = f;
    return (unsigned short)((v.u + 0x7fffu + ((v.u >> 16) & 1u)) >> 16);
}
static __device__ __forceinline__ unsigned fbits(float f) {
    union { float f; unsigned u; } v; v.f = f; return v.u;
}

// ---------------------------------------------------------------------------
// Kernel 1: unchanged from R4/R6 except log2e folded into the Q weights.
// ---------------------------------------------------------------------------
__global__ __launch_bounds__(256, 2) void proj_kernel(
    const float* __restrict__ x,
    const float* __restrict__ dw_q, const float* __restrict__ pw_q,
    const float* __restrict__ dw_k, const float* __restrict__ pw_k,
    const float* __restrict__ dw_v, const float* __restrict__ pw_v,
    unsigned short* __restrict__ qf_ws, unsigned short* __restrict__ kt,
    unsigned short* __restrict__ vt)
{
    __shared__ unsigned short xT[128 * 136];  // xT[n][c]
    __shared__ unsigned short Ws[128 * 136];  // W[o][c]; reused as store scratch

    const int bid = blockIdx.x;
    const int bb  = bid & 7;
    const int t   = (bid >> 3) & 31;
    const int pp  = bid >> 8;            // 0:q 1:k 2:v
    const int n0  = t * 128;
    const int tid = threadIdx.x;
    const int w    = tid >> 6;
    const int lane = tid & 63;
    const int quad = lane >> 4;
    const int l16  = lane & 15;

    #pragma unroll
    for (int k = 0; k < 16; ++k) {
        const int idx = tid + k * 256;
        const int c  = idx >> 5;
        const int nq = idx & 31;
        float4 f = *(const float4*)(x + ((size_t)(bb * C_ + c)) * N_ + n0 + nq * 4);
        xT[(nq * 4 + 0) * 136 + c] = f2bf_rne(f.x);
        xT[(nq * 4 + 1) * 136 + c] = f2bf_rne(f.y);
        xT[(nq * 4 + 2) * 136 + c] = f2bf_rne(f.z);
        xT[(nq * 4 + 3) * 136 + c] = f2bf_rne(f.w);
    }
    const float* pw = (pp == 0) ? pw_q : (pp == 1) ? pw_k : pw_v;
    const float* dw = (pp == 0) ? dw_q : (pp == 1) ? dw_k : dw_v;
    // Fold log2(e) into the Q weights: attn then uses exp2 (bare v_exp_f32)
    // instead of mul+exp. S has sigma ~0.09 so no range concern.
    const float qs = (pp == 0) ? 1.4426950408889634f : 1.0f;
    #pragma unroll
    for (int k = 0; k < 16; ++k) {
        const int idx = tid + k * 256;
        const int o  = idx >> 5;
        const int c4 = (idx & 31) * 4;
        float4 p4 = *(const float4*)(pw + o * 128 + c4);
        float4 d4 = *(const float4*)(dw + c4);
        unsigned lo = (unsigned)f2bf_rne(p4.x * d4.x * qs) | ((unsigned)f2bf_rne(p4.y * d4.y * qs) << 16);
        unsigned hi = (unsigned)f2bf_rne(p4.z * d4.z * qs) | ((unsigned)f2bf_rne(p4.w * d4.w * qs) << 16);
        *(unsigned long long*)&Ws[o * 136 + c4] =
            (unsigned long long)lo | ((unsigned long long)hi << 32);
    }
    __syncthreads();

    const unsigned short* As = (pp < 2) ? xT : Ws;
    const unsigned short* Bs = (pp < 2) ? Ws : xT;

    v4f acc[2][8];
    #pragma unroll
    for (int i = 0; i < 2; ++i)
        #pragma unroll
        for (int j = 0; j < 8; ++j)
            acc[i][j] = (v4f){0.f, 0.f, 0.f, 0.f};

    #pragma unroll
    for (int kc = 0; kc < 4; ++kc) {
        v8bf av[2];
        #pragma unroll
        for (int i = 0; i < 2; ++i)
            av[i] = *(const v8bf*)&As[(w * 32 + i * 16 + l16) * 136 + kc * 32 + quad * 8];
        #pragma unroll
        for (int cb = 0; cb < 8; ++cb) {
            v8bf bv = *(const v8bf*)&Bs[(cb * 16 + l16) * 136 + kc * 32 + quad * 8];
            acc[0][cb] = __builtin_amdgcn_mfma_f32_16x16x32_bf16(av[0], bv, acc[0][cb], 0, 0, 0);
            acc[1][cb] = __builtin_amdgcn_mfma_f32_16x16x32_bf16(av[1], bv, acc[1][cb], 0, 0, 0);
        }
    }
    __syncthreads();

    unsigned short* sc = Ws;
    #pragma unroll
    for (int mi = 0; mi < 2; ++mi)
        #pragma unroll
        for (int cb = 0; cb < 8; ++cb)
            #pragma unroll
            for (int r = 0; r < 4; ++r)
                sc[(w * 32 + mi * 16 + quad * 4 + r) * 136 + cb * 16 + l16] =
                    f2bf_rne(acc[mi][cb][r]);
    __syncthreads();

    if (pp == 0) {
        unsigned short* dst = qf_ws + ((size_t)(bb * 64 + t * 2)) * 8192;
        #pragma unroll
        for (int p = 0; p < 8; ++p) {
            const int g     = p * 4 + w;
            const int strip = g >> 4, ni = (g >> 2) & 3, kc = g & 3;
            *(uint4*)(dst + ((size_t)g * 64 + lane) * 8) =
                *(const uint4*)&sc[(strip * 64 + ni * 16 + l16) * 136 + kc * 32 + quad * 8];
        }
    } else if (pp == 1) {
        unsigned short* dst = kt + ((size_t)(bb * 32 + t)) * 16384;
        #pragma unroll
        for (int p = 0; p < 8; ++p) {
            const int g  = p * 4 + w;
            const int mb = g >> 2, kc = g & 3;
            *(uint4*)(dst + ((size_t)g * 64 + lane) * 8) =
                *(const uint4*)&sc[(mb * 16 + l16) * 136 + kc * 32 + quad * 8];
        }
    } else {
        unsigned short* dst = vt + ((size_t)(bb * 32 + t)) * 16384;
        #pragma unroll
        for (int p = 0; p < 8; ++p) {
            const int d  = p * 256 + tid;
            const int cb = d >> 8, wq = (d >> 4) & 15, l = d & 15;
            *(uint4*)(dst + (size_t)d * 8) =
                *(const uint4*)&sc[(cb * 16 + l) * 136 + wq * 8];
        }
    }
}

// ---------------------------------------------------------------------------
// Kernel 2: attention. grid 1024 = (b = bid&7, 32-row n-strip = bid>>3).
// 256 thr / 4 waves; wave = m-quarter, full c=128, n=32.
// R7 pipeline: dual sacc banks. Each half-step runs softmax(tile t)
// INTERLEAVED with the S-MFMAs of tile t+1, then PV(t). K register ping-pong
// 2 tiles ahead; V single-buffered (reloaded right after PV consumes it,
// hidden by the following LOADK+FUSED phase). Zero LDS/barriers in main loop.
// ---------------------------------------------------------------------------
#define MFMA(A, B, C) __builtin_amdgcn_mfma_f32_16x16x32_bf16(A, B, C, 0, 0, 0)
#define EXP2(X) __builtin_amdgcn_exp2f(X)
#define PKPERM(EH, EL) __builtin_amdgcn_perm(fbits(EH), fbits(EL), 0x07060302)

#define LOADK(KF, TILE) { \
    const unsigned short* kp_ = kbase + (size_t)(TILE) * 16384; \
    _Pragma("unroll") \
    for (int mi_ = 0; mi_ < 2; ++mi_) \
        _Pragma("unroll") \
        for (int kc_ = 0; kc_ < 4; ++kc_) \
            KF[mi_][kc_] = *(const v8bf*)(kp_ + (size_t)((mi_ * 4 + kc_) * 64) * 8); \
}

#define LOADV(TILE) { \
    const unsigned short* vp_ = vbase + (size_t)(TILE) * 16384; \
    _Pragma("unroll") \
    for (int cb_ = 0; cb_ < 8; ++cb_) \
        vf[cb_] = *(const v8bf*)(vp_ + (size_t)(cb_ * 256) * 8); \
}

// Build pf[NI] from the packed bf16 exp pairs of both mi halves (unchanged
// data movement from R6: dest quads {0,1} take mi=0, {2,3} take mi=1, cross-
// quad redistribution via ds_bpermute).
#define MKPF(NI, PK0A, PK0B, PK1A, PK1B) { \
    unsigned sLo_ = (quad < 2) ? PK0A : PK1A; \
    unsigned sHi_ = (quad < 2) ? PK0B : PK1B; \
    union { unsigned u[4]; v8bf v; } pu_; \
    pu_.u[0] = (unsigned)__builtin_amdgcn_ds_bpermute(la, (int)sLo_); \
    pu_.u[1] = (unsigned)__builtin_amdgcn_ds_bpermute(la, (int)sHi_); \
    pu_.u[2] = (unsigned)__builtin_amdgcn_ds_bpermute(lb, (int)sLo_); \
    pu_.u[3] = (unsigned)__builtin_amdgcn_ds_bpermute(lb, (int)sHi_); \
    pf[NI] = pu_.v; \
}

// Prologue-only plain S compute (zero-init via Z4v in the kc=0 MFMA).
#define SCOMP0(KF, SC) { \
    _Pragma("unroll") \
    for (int mi_ = 0; mi_ < 2; ++mi_) \
        _Pragma("unroll") \
        for (int ni_ = 0; ni_ < 2; ++ni_) { \
            v4f a_ = MFMA(KF[mi_][0], qf[ni_][0], Z4v); \
            _Pragma("unroll") \
            for (int kc_ = 1; kc_ < 4; ++kc_) \
                a_ = MFMA(KF[mi_][kc_], qf[ni_][kc_], a_); \
            SC[mi_][ni_] = a_; \
        } \
}

// Fused: softmax of SC_IN (previous tile) hand-interleaved, in program order,
// with the 16 S-MFMAs of the next tile (KF -> SC_OUT). In-order issue means
// each MFMA pair's ~2x19cy pipe occupancy covers the adjacent VALU chunk.
#define FUSED(SC_IN, KF, SC_OUT) { \
    float e0_, e1_, e2_, e3_; \
    unsigned pk00a_, pk00b_, pk10a_, pk10b_, pk01a_, pk01b_, pk11a_, pk11b_; \
    /* slot 0: kc0 (zero-init) + exps of group (mi0,ni0) */ \
    SC_OUT[0][0] = MFMA(KF[0][0], qf[0][0], Z4v); \
    SC_OUT[0][1] = MFMA(KF[0][0], qf[1][0], Z4v); \
    e0_ = EXP2(SC_IN[0][0][0]); e1_ = EXP2(SC_IN[0][0][1]); \
    e2_ = EXP2(SC_IN[0][0][2]); e3_ = EXP2(SC_IN[0][0][3]); \
    /* slot 1 */ \
    SC_OUT[0][0] = MFMA(KF[0][1], qf[0][1], SC_OUT[0][0]); \
    SC_OUT[0][1] = MFMA(KF[0][1], qf[1][1], SC_OUT[0][1]); \
    lpart[0] += (e0_ + e1_) + (e2_ + e3_); \
    pk00a_ = PKPERM(e1_, e0_); pk00b_ = PKPERM(e3_, e2_); \
    /* slot 2: exps of group (mi1,ni0) */ \
    SC_OUT[0][0] = MFMA(KF[0][2], qf[0][2], SC_OUT[0][0]); \
    SC_OUT[0][1] = MFMA(KF[0][2], qf[1][2], SC_OUT[0][1]); \
    e0_ = EXP2(SC_IN[1][0][0]); e1_ = EXP2(SC_IN[1][0][1]); \
    e2_ = EXP2(SC_IN[1][0][2]); e3_ = EXP2(SC_IN[1][0][3]); \
    /* slot 3 */ \
    SC_OUT[0][0] = MFMA(KF[0][3], qf[0][3], SC_OUT[0][0]); \
    SC_OUT[0][1] = MFMA(KF[0][3], qf[1][3], SC_OUT[0][1]); \
    lpart[0] += (e0_ + e1_) + (e2_ + e3_); \
    pk10a_ = PKPERM(e1_, e0_); pk10b_ = PKPERM(e3_, e2_); \
    /* slot 4: pf[0] bpermutes fly under the mi1 MFMAs */ \
    SC_OUT[1][0] = MFMA(KF[1][0], qf[0][0], Z4v); \
    SC_OUT[1][1] = MFMA(KF[1][0], qf[1][0], Z4v); \
    MKPF(0, pk00a_, pk00b_, pk10a_, pk10b_) \
    /* slot 5: exps of group (mi0,ni1) */ \
    SC_OUT[1][0] = MFMA(KF[1][1], qf[0][1], SC_OUT[1][0]); \
    SC_OUT[1][1] = MFMA(KF[1][1], qf[1][1], SC_OUT[1][1]); \
    e0_ = EXP2(SC_IN[0][1][0]); e1_ = EXP2(SC_IN[0][1][1]); \
    e2_ = EXP2(SC_IN[0][1][2]); e3_ = EXP2(SC_IN[0][1][3]); \
    /* slot 6 */ \
    SC_OUT[1][0] = MFMA(KF[1][2], qf[0][2], SC_OUT[1][0]); \
    SC_OUT[1][1] = MFMA(KF[1][2], qf[1][2], SC_OUT[1][1]); \
    lpart[1] += (e0_ + e1_) + (e2_ + e3_); \
    pk01a_ = PKPERM(e1_, e0_); pk01b_ = PKPERM(e3_, e2_); \
    /* slot 7: exps of group (mi1,ni1) */ \
    SC_OUT[1][0] = MFMA(KF[1][3], qf[0][3], SC_OUT[1][0]); \
    SC_OUT[1][1] = MFMA(KF[1][3], qf[1][3], SC_OUT[1][1]); \
    e0_ = EXP2(SC_IN[1][1][0]); e1_ = EXP2(SC_IN[1][1][1]); \
    e2_ = EXP2(SC_IN[1][1][2]); e3_ = EXP2(SC_IN[1][1][3]); \
    lpart[1] += (e0_ + e1_) + (e2_ + e3_); \
    pk11a_ = PKPERM(e1_, e0_); pk11b_ = PKPERM(e3_, e2_); \
    MKPF(1, pk01a_, pk01b_, pk11a_, pk11b_) \
}

// PV ni-outer: pf[0]'s MFMAs issue while pf[1]'s bpermutes drain.
#define PVOP { \
    _Pragma("unroll") \
    for (int ni_ = 0; ni_ < 2; ++ni_) \
        _Pragma("unroll") \
        for (int cb_ = 0; cb_ < 8; ++cb_) \
            oacc[cb_][ni_] = MFMA(vf[cb_], pf[ni_], oacc[cb_][ni_]); \
}

__global__ __launch_bounds__(256, 2) void attn_kernel(
    const unsigned short* __restrict__ qf_ws, const unsigned short* __restrict__ kt,
    const unsigned short* __restrict__ vt, const float* __restrict__ x,
    const float* __restrict__ gamma, float* __restrict__ out)
{
    __shared__ float red[32 * 132];   // O reduction scratch [n][c] (+pad)
    __shared__ float l_s[4][32];

    const int bid = blockIdx.x;
    const int bb  = bid & 7;
    const int s   = bid >> 3;        // n-strip 0..127 (32 rows each)
    const int n0  = s * 32;
    const int tid = threadIdx.x;
    const int w    = tid >> 6;       // wave = m-quarter owner
    const int lane = tid & 63;
    const int quad = lane >> 4;
    const int l16  = lane & 15;

    // ---- Q fragments (n=32 strip): 32 VGPR, iteration-invariant
    v8bf qf[2][4];
    {
        const unsigned short* qb = qf_ws + ((size_t)(bb * 128 + s)) * 4096;
        #pragma unroll
        for (int ni = 0; ni < 2; ++ni)
            #pragma unroll
            for (int kc = 0; kc < 4; ++kc)
                qf[ni][kc] = *(const v8bf*)(qb + ((size_t)(ni * 4 + kc) * 64 + lane) * 8);
    }

    v4f oacc[8][2];  // 64 regs: [cb][ni] partial O over this wave's 32-m subset
    #pragma unroll
    for (int i = 0; i < 8; ++i)
        #pragma unroll
        for (int j = 0; j < 2; ++j)
            oacc[i][j] = (v4f){0.f, 0.f, 0.f, 0.f};
    float lpart[2] = {0.f, 0.f};
    const v4f Z4v = {0.f, 0.f, 0.f, 0.f};

    const int la = ((((quad & 1) << 1) << 4) + l16) << 2;  // bpermute byte idx
    const int lb = la + 64;

    const unsigned short* kbase = kt + ((size_t)(bb * 32)) * 16384 + ((size_t)(w * 8) * 64 + lane) * 8;
    const unsigned short* vbase = vt + ((size_t)(bb * 32)) * 16384 + ((size_t)(w * 64 + lane)) * 8;

    v8bf kfA[2][4], kfB[2][4], vf[8];
    v4f sc0[2][2], sc1[2][2];
    v8bf pf[2];

    LOADK(kfA, 0)
    LOADV(0)
    LOADK(kfB, 1)
    SCOMP0(kfA, sc0)                 // S(0)

    for (int it = 0; it < 32; it += 2) {
        LOADK(kfA, (it + 2) & 31)    // K(t+2) in flight across this half-step
        FUSED(sc0, kfB, sc1)         // softmax(t) || S(t+1)
        PVOP                          // PV(t), consumes vf = V(t)
        LOADV((it + 1) & 31)
        LOADK(kfB, (it + 3) & 31)
        FUSED(sc1, kfA, sc0)         // softmax(t+1) || S(t+2)
        PVOP                          // PV(t+1)
        LOADV((it + 2) & 31)
    }

    // ---- softmax denominators (per-wave partials over its 32-m subset)
    #pragma unroll
    for (int ni = 0; ni < 2; ++ni) {
        float r = lpart[ni];
        r += __shfl_xor(r, 16);
        r += __shfl_xor(r, 32);
        if (lane < 16) l_s[w][ni * 16 + lane] = r;
    }

    // ---- O reduction across the 4 m-quarter waves
    for (int rw = 0; rw < 4; ++rw) {
        if (w == rw) {
            #pragma unroll
            for (int cb = 0; cb < 8; ++cb)
                #pragma unroll
                for (int ni = 0; ni < 2; ++ni) {
                    float* p = &red[(ni * 16 + l16) * 132 + cb * 16 + quad * 4];
                    if (rw == 0) *(v4f*)p = oacc[cb][ni];
                    else {
                        v4f tv = *(const v4f*)p;
                        tv += oacc[cb][ni];
                        *(v4f*)p = tv;
                    }
                }
        }
        __syncthreads();
    }

    // ---- epilogue: out = gamma * O / l + x  (thread: n = tid&31, c-group = tid>>5)
    const float g = gamma[0];
    const int   n = tid & 31;
    const int  cg = tid >> 5;        // 0..7
    const float li = 1.0f / (((l_s[0][n] + l_s[1][n]) + (l_s[2][n] + l_s[3][n])));
    #pragma unroll
    for (int j = 0; j < 16; ++j) {
        const int c = cg * 16 + j;
        const size_t idx = ((size_t)(bb * C_ + c)) * N_ + n0 + n;
        out[idx] = g * red[n * 132 + c] * li + x[idx];
    }
}

// ---------------------------------------------------------------------------
extern "C" void kernel_launch(void* const* d_in, const int* in_sizes, int n_in,
                              void* d_out, int out_size, void* d_ws, size_t ws_size,
                              hipStream_t stream)
{
    (void)in_sizes; (void)n_in; (void)out_size; (void)ws_size;
    const float* x     = (const float*)d_in[0];
    const float* dw_q  = (const float*)d_in[1];
    const float* pw_q  = (const float*)d_in[2];
    const float* dw_k  = (const float*)d_in[3];
    const float* pw_k  = (const float*)d_in[4];
    const float* dw_v  = (const float*)d_in[5];
    const float* pw_v  = (const float*)d_in[6];
    const float* gamma = (const float*)d_in[7];
    float* out = (float*)d_out;

    unsigned short* qf_ws = (unsigned short*)d_ws;                  // 8 MB
    unsigned short* kt    = qf_ws + (size_t)B_ * N_ * C_;           // 8 MB
    unsigned short* vt    = kt    + (size_t)B_ * N_ * C_;           // 8 MB

    proj_kernel<<<dim3(768), dim3(256), 0, stream>>>(
        x, dw_q, pw_q, dw_k, pw_k, dw_v, pw_v, qf_ws, kt, vt);
    attn_kernel<<<dim3(1024), dim3(256), 0, stream>>>(
        qf_ws, kt, vt, x, gamma, out);
}